// Round 1
// 324.917 us; speedup vs baseline: 1.0078x; 1.0078x over previous
//
#include <hip/hip_runtime.h>

// ---------------------------------------------------------------------------
// QuaternionLinear == one GEMM: out[M=32768][N=1024] = x[M][K=1024] * W^T + b.
// (1) cvt x fp32->bf16, (2) build combined bf16 W (B^T layout),
// (3) 256x256-tile BK=64 8-wave MFMA GEMM using the verified 8-phase
//     schedule (T2 st_16x32 LDS swizzle + T3/T4 counted vmcnt + T5 setprio
//     + T1 XCD swizzle), fp32 accumulate, bias fused in epilogue.
// ---------------------------------------------------------------------------

typedef __attribute__((ext_vector_type(8))) short bf16x8;   // 8 bf16 = 4 VGPRs
typedef __attribute__((ext_vector_type(4))) float f32x4;

#define M_TOT 32768
#define N_TOT 1024
#define K_TOT 1024
#define BM 256
#define BN 256
#define BK 64
#define NKT (K_TOT / BK)   // 16 K-tiles

__device__ __forceinline__ unsigned short f2bf(float f) {
    union { float f; unsigned int u; } v; v.f = f;
    unsigned int u = v.u;
    u += 0x7fffu + ((u >> 16) & 1u);   // round-to-nearest-even
    return (unsigned short)(u >> 16);
}

// ---- kernel 1: x fp32 -> bf16 (16B read, 8B write per lane) ---------------
__global__ __launch_bounds__(256) void cvt_x(const float4* __restrict__ x,
                                             ushort4* __restrict__ y) {
    int idx = blockIdx.x * 256 + threadIdx.x;   // exact: no bounds needed
    float4 a = x[idx];
    ushort4 o;
    o.x = f2bf(a.x); o.y = f2bf(a.y); o.z = f2bf(a.z); o.w = f2bf(a.w);
    y[idx] = o;
}

// ---- kernel 2: combined quaternion weight matrix, bf16, [N][K] (B^T) ------
__global__ __launch_bounds__(256) void build_w(const float* __restrict__ R,
                                               const float* __restrict__ I,
                                               const float* __restrict__ J,
                                               const float* __restrict__ Kw,
                                               ushort4* __restrict__ Wb) {
    int n = blockIdx.x;          // 0..1023 (output row of W)
    int i = threadIdx.x;         // 0..255  (input quaternion index)
    int o = n >> 2, co = n & 3;
    int base = o * 256 + i;
    float r = R[base], ii = I[base], j = J[base], k = Kw[base];
    float v0, v1, v2, v3;
    if (co == 0)      { v0 = r;  v1 = -ii; v2 = -j;  v3 = -k; }
    else if (co == 1) { v0 = ii; v1 = r;   v2 = k;   v3 = -j; }
    else if (co == 2) { v0 = j;  v1 = -k;  v2 = r;   v3 = ii; }
    else              { v0 = k;  v1 = j;   v2 = -ii; v3 = r;  }
    ushort4 w;
    w.x = f2bf(v0); w.y = f2bf(v1); w.z = f2bf(v2); w.w = f2bf(v3);
    Wb[n * 256 + i] = w;         // coalesced 8B/lane
}

// ---- kernel 3: 256x256-tile 8-phase bf16 MFMA GEMM ------------------------
__device__ __forceinline__ void async_lds16(const void* g, void* l) {
    __builtin_amdgcn_global_load_lds(
        (const __attribute__((address_space(1))) unsigned int*)g,
        (__attribute__((address_space(3))) unsigned int*)l,
        16, 0, 0);
}

// Stage one half-tile (128 rows x 64 bf16 cols) of G (leading dim K_TOT)
// into an 8192-short LDS half-tile laid out as 16 subtiles of [16][32] bf16
// (1024B each, = one wave-instruction of global_load_lds width 16).
// Swizzle: logical byte L stores at L ^ (((L>>9)&1)<<5)  (st_16x32).
// global_load_lds writes LINEAR (base + lane*16), so we inverse-swizzle the
// per-lane GLOBAL source address (both-sides-or-neither rule, m231).
__device__ __forceinline__ void stage_ht(const unsigned short* __restrict__ G,
                                         int row0, int k0,
                                         unsigned short* ht,
                                         int wave, int lane) {
    int sr = lane >> 2;                                     // subtile row 0..15
    int sc = ((lane & 3) * 8) ^ ((lane & 32) ? 16 : 0);     // swizzled col (elems)
#pragma unroll
    for (int j = 0; j < 2; ++j) {
        int si = j * 8 + wave;           // subtile 0..15
        int rg = si >> 1, cg = si & 1;   // row-group (16 rows), col-group (32 cols)
        async_lds16(G + (size_t)(row0 + rg * 16 + sr) * K_TOT + k0 + cg * 32 + sc,
                    ht + si * 512);      // wave-uniform LDS base, lane*16 implicit
    }
}

// Read one MFMA A/B fragment (8 contiguous bf16 at [row][kk + quad*8]) from a
// swizzled half-tile.  row 0..127 within HT, kk in {0,32}.
__device__ __forceinline__ bf16x8 frag_ld(const unsigned short* ht,
                                          int row, int kk, int quad) {
    int idx = (((row >> 4) << 1) + (kk >> 5)) * 512 + (row & 15) * 32 + quad * 8;
    idx ^= (row & 8) << 1;               // (row%16)>=8 -> XOR 16 shorts (byte bit5)
    return *(const bf16x8*)(ht + idx);
}

__global__ __launch_bounds__(512, 2) void gemm_bt(
        const unsigned short* __restrict__ A,   // [M][K] bf16
        const unsigned short* __restrict__ B,   // [N][K] bf16
        const float* __restrict__ bias,         // [N]
        float* __restrict__ C) {                // [M][N] fp32
    // [buf][A=0|B=1][half][8192 shorts] = 128 KiB total -> 1 block/CU
    __shared__ unsigned short smem[2][2][2][8192];

    const int tid  = threadIdx.x;
    const int wave = tid >> 6;      // 0..7
    const int lane = tid & 63;
    const int quad = lane >> 4;     // 0..3
    const int r16  = lane & 15;     // 0..15
    const int wm   = wave & 1;      // wave grid 2(M) x 4(N); each wave: 128x64 out
    const int wn   = wave >> 1;     // 0..3

    // T1: bijective XCD swizzle (512 workgroups, 512 % 8 == 0)
    int bid = blockIdx.x;
    int wg  = (bid & 7) * 64 + (bid >> 3);
    const int m0 = (wg >> 2) * BM;  // 128 M-tiles
    const int n0 = (wg & 3) * BN;   // 4 N-tiles (consecutive wg share A panel)

    f32x4 acc[8][4];
#pragma unroll
    for (int i = 0; i < 8; ++i)
#pragma unroll
        for (int j = 0; j < 4; ++j)
            acc[i][j] = (f32x4){0.f, 0.f, 0.f, 0.f};

    const int brow0 = (wn & 1) * 64;     // this wave's row base inside its B-HT

    // ---- prologue: tile0 full (A0,A1,B0,B1) + tile1 A halves; vmcnt(4)
    // leaves tile1's A in flight, publishes tile0 at the barrier.
    stage_ht(A, m0,        0, &smem[0][0][0][0], wave, lane);
    stage_ht(A, m0 + 128,  0, &smem[0][0][1][0], wave, lane);
    stage_ht(B, n0,        0, &smem[0][1][0][0], wave, lane);
    stage_ht(B, n0 + 128,  0, &smem[0][1][1][0], wave, lane);
    stage_ht(A, m0,       BK, &smem[1][0][0][0], wave, lane);
    stage_ht(A, m0 + 128, BK, &smem[1][0][1][0], wave, lane);
    asm volatile("s_waitcnt vmcnt(4)" ::: "memory");
    __builtin_amdgcn_s_barrier();

    bf16x8 af[4][2], bl[2][2], bh[2][2];

#pragma unroll 2
    for (int t = 0; t < NKT; ++t) {
        const int c = t & 1;
        const unsigned short* Ah = &smem[c][0][wm][0];
        const unsigned short* Bh = &smem[c][1][wn >> 1][0];

        // ---------- P1: read A[m0-3], B[n0-1]; stage (t+1) B halves ----------
#pragma unroll
        for (int mb = 0; mb < 4; ++mb) {
            af[mb][0] = frag_ld(Ah, mb * 16 + r16, 0, quad);
            af[mb][1] = frag_ld(Ah, mb * 16 + r16, 32, quad);
        }
#pragma unroll
        for (int nb = 0; nb < 2; ++nb) {
            bl[nb][0] = frag_ld(Bh, brow0 + nb * 16 + r16, 0, quad);
            bl[nb][1] = frag_ld(Bh, brow0 + nb * 16 + r16, 32, quad);
        }
        if (t + 1 < NKT) {      // buf(c^1) B slots freed after tile t-1's P2
            stage_ht(B, n0,       (t + 1) * BK, &smem[c ^ 1][1][0][0], wave, lane);
            stage_ht(B, n0 + 128, (t + 1) * BK, &smem[c ^ 1][1][1][0], wave, lane);
        }
        __builtin_amdgcn_s_barrier();
        asm volatile("s_waitcnt lgkmcnt(0)" ::: "memory");
        __builtin_amdgcn_s_setprio(1);
#pragma unroll
        for (int mb = 0; mb < 4; ++mb)
#pragma unroll
            for (int nb = 0; nb < 2; ++nb) {
                acc[mb][nb] = __builtin_amdgcn_mfma_f32_16x16x32_bf16(
                    af[mb][0], bl[nb][0], acc[mb][nb], 0, 0, 0);
                acc[mb][nb] = __builtin_amdgcn_mfma_f32_16x16x32_bf16(
                    af[mb][1], bl[nb][1], acc[mb][nb], 0, 0, 0);
            }
        __builtin_amdgcn_s_setprio(0);
        __builtin_amdgcn_s_barrier();

        // ---------- P2: read B[n2-3] ----------
#pragma unroll
        for (int nb = 0; nb < 2; ++nb) {
            bh[nb][0] = frag_ld(Bh, brow0 + (nb + 2) * 16 + r16, 0, quad);
            bh[nb][1] = frag_ld(Bh, brow0 + (nb + 2) * 16 + r16, 32, quad);
        }
        __builtin_amdgcn_s_barrier();
        asm volatile("s_waitcnt lgkmcnt(0)" ::: "memory");
        __builtin_amdgcn_s_setprio(1);
#pragma unroll
        for (int mb = 0; mb < 4; ++mb)
#pragma unroll
            for (int nb = 0; nb < 2; ++nb) {
                acc[mb][nb + 2] = __builtin_amdgcn_mfma_f32_16x16x32_bf16(
                    af[mb][0], bh[nb][0], acc[mb][nb + 2], 0, 0, 0);
                acc[mb][nb + 2] = __builtin_amdgcn_mfma_f32_16x16x32_bf16(
                    af[mb][1], bh[nb][1], acc[mb][nb + 2], 0, 0, 0);
            }
        __builtin_amdgcn_s_setprio(0);
        __builtin_amdgcn_s_barrier();

        // ---------- P3: read A[m4-7] (A slots become free after this) --------
#pragma unroll
        for (int mb = 0; mb < 4; ++mb) {
            af[mb][0] = frag_ld(Ah, 64 + mb * 16 + r16, 0, quad);
            af[mb][1] = frag_ld(Ah, 64 + mb * 16 + r16, 32, quad);
        }
        __builtin_amdgcn_s_barrier();
        asm volatile("s_waitcnt lgkmcnt(0)" ::: "memory");
        __builtin_amdgcn_s_setprio(1);
#pragma unroll
        for (int mb = 0; mb < 4; ++mb)
#pragma unroll
            for (int nb = 0; nb < 2; ++nb) {
                acc[mb + 4][nb + 2] = __builtin_amdgcn_mfma_f32_16x16x32_bf16(
                    af[mb][0], bh[nb][0], acc[mb + 4][nb + 2], 0, 0, 0);
                acc[mb + 4][nb + 2] = __builtin_amdgcn_mfma_f32_16x16x32_bf16(
                    af[mb][1], bh[nb][1], acc[mb + 4][nb + 2], 0, 0, 0);
            }
        __builtin_amdgcn_s_setprio(0);
        __builtin_amdgcn_s_barrier();

        // ---------- P4: stage (t+2) A halves; MFMA from regs; counted vmcnt --
        if (t + 2 < NKT) {      // buf(c) A slots freed by P3's end barrier
            stage_ht(A, m0,       (t + 2) * BK, &smem[c][0][0][0], wave, lane);
            stage_ht(A, m0 + 128, (t + 2) * BK, &smem[c][0][1][0], wave, lane);
        }
        __builtin_amdgcn_s_barrier();
        __builtin_amdgcn_s_setprio(1);
#pragma unroll
        for (int mb = 0; mb < 4; ++mb)
#pragma unroll
            for (int nb = 0; nb < 2; ++nb) {
                acc[mb + 4][nb] = __builtin_amdgcn_mfma_f32_16x16x32_bf16(
                    af[mb][0], bl[nb][0], acc[mb + 4][nb], 0, 0, 0);
                acc[mb + 4][nb] = __builtin_amdgcn_mfma_f32_16x16x32_bf16(
                    af[mb][1], bl[nb][1], acc[mb + 4][nb], 0, 0, 0);
            }
        __builtin_amdgcn_s_setprio(0);
        // publish tile t+1 (its B staged at P1, its A at previous P4), keep
        // t+2's A (4 loads) in flight -> vmcnt(4), never 0 in steady state.
        if (t + 2 < NKT) {
            asm volatile("s_waitcnt vmcnt(4)" ::: "memory");
        } else if (t + 1 < NKT) {
            asm volatile("s_waitcnt vmcnt(0)" ::: "memory");   // tail drain
        }
        __builtin_amdgcn_s_barrier();
    }

    // ---- epilogue: C/D layout col = lane&15 (N), row = quad*4 + reg (M) ----
    const int mbase = m0 + wm * 128 + quad * 4;
    const int nbase = n0 + wn * 64 + r16;
#pragma unroll
    for (int nb = 0; nb < 4; ++nb) {
        int col  = nbase + nb * 16;
        float bv = bias[col];
#pragma unroll
        for (int mb = 0; mb < 8; ++mb) {
            int rowb = mbase + mb * 16;
            f32x4 v  = acc[mb][nb];
#pragma unroll
            for (int r = 0; r < 4; ++r)
                C[(size_t)(rowb + r) * N_TOT + col] = v[r] + bv;
        }
    }
}

extern "C" void kernel_launch(void* const* d_in, const int* in_sizes, int n_in,
                              void* d_out, int out_size, void* d_ws, size_t ws_size,
                              hipStream_t stream) {
    const float* x    = (const float*)d_in[0];   // [4, 8192, 1024]
    const float* rw   = (const float*)d_in[1];   // [256, 256]
    const float* iw   = (const float*)d_in[2];
    const float* jw   = (const float*)d_in[3];
    const float* kw   = (const float*)d_in[4];
    const float* bias = (const float*)d_in[5];   // [1024]
    float* out = (float*)d_out;                  // [4, 8192, 1024]

    // workspace: [0, 64 MiB) x in bf16; [64 MiB, 66 MiB) combined W in bf16
    unsigned short* xb = (unsigned short*)d_ws;
    unsigned short* Wb = (unsigned short*)((char*)d_ws + (size_t)M_TOT * K_TOT * 2);

    // 1) convert x -> bf16 (33.5M elems, 4/thread)
    cvt_x<<<(M_TOT * (size_t)K_TOT) / 4 / 256, 256, 0, stream>>>(
        (const float4*)x, (ushort4*)xb);

    // 2) build combined 1024x1024 bf16 weight (B^T layout), 1 block/row
    build_w<<<N_TOT, 256, 0, stream>>>(rw, iw, jw, kw, (ushort4*)Wb);

    // 3) GEMM: 128 x 4 tiles of 256x256, 512 threads (8 waves)
    gemm_bt<<<dim3((M_TOT / BM) * (N_TOT / BN)), 512, 0, stream>>>(
        xb, Wb, bias, out);
}

// Round 2
// 315.320 us; speedup vs baseline: 1.0385x; 1.0304x over previous
//
#include <hip/hip_runtime.h>

// ---------------------------------------------------------------------------
// QuaternionLinear == one GEMM: out[M=32768][N=1024] = x[M][K=1024] * W^T + b.
// Round 2: cvt_x is FUSED into the GEMM (A reg-staged fp32->bf16 with
// swizzled ds_write, quarter-tile staggered issue/consume); B stays
// global_load_lds with pre-swizzled source.  256x256 tile, BK=64, 8 waves,
// 4 phases/K-tile, counted vmcnt (auto via staggered reg consumption),
// setprio around MFMA, bijective XCD swizzle, all LDS addressing reduced to
// 2 lane-base registers + compile-time immediate offsets.
// ---------------------------------------------------------------------------

typedef __attribute__((ext_vector_type(8))) short bf16x8;   // 8 bf16 = 4 VGPRs
typedef __attribute__((ext_vector_type(4))) float f32x4;

#define M_TOT 32768
#define N_TOT 1024
#define K_TOT 1024
#define BM 256
#define BN 256
#define BK 64
#define NKT (K_TOT / BK)   // 16 K-tiles

__device__ __forceinline__ unsigned short f2bf(float f) {
    union { float f; unsigned int u; } v; v.f = f;
    unsigned int u = v.u;
    u += 0x7fffu + ((u >> 16) & 1u);   // round-to-nearest-even
    return (unsigned short)(u >> 16);
}

__device__ __forceinline__ bf16x8 cvt8(float4 a, float4 b) {
    bf16x8 r;
    r[0] = (short)f2bf(a.x); r[1] = (short)f2bf(a.y);
    r[2] = (short)f2bf(a.z); r[3] = (short)f2bf(a.w);
    r[4] = (short)f2bf(b.x); r[5] = (short)f2bf(b.y);
    r[6] = (short)f2bf(b.z); r[7] = (short)f2bf(b.w);
    return r;
}

// ---- kernel 1: combined quaternion weight matrix, bf16, [N][K] (B^T) ------
__global__ __launch_bounds__(256) void build_w(const float* __restrict__ R,
                                               const float* __restrict__ I,
                                               const float* __restrict__ J,
                                               const float* __restrict__ Kw,
                                               ushort4* __restrict__ Wb) {
    int n = blockIdx.x;          // 0..1023 (output row of W)
    int i = threadIdx.x;         // 0..255  (input quaternion index)
    int o = n >> 2, co = n & 3;
    int base = o * 256 + i;
    float r = R[base], ii = I[base], j = J[base], k = Kw[base];
    float v0, v1, v2, v3;
    if (co == 0)      { v0 = r;  v1 = -ii; v2 = -j;  v3 = -k; }
    else if (co == 1) { v0 = ii; v1 = r;   v2 = k;   v3 = -j; }
    else if (co == 2) { v0 = j;  v1 = -k;  v2 = r;   v3 = ii; }
    else              { v0 = k;  v1 = j;   v2 = -ii; v3 = r;  }
    ushort4 w;
    w.x = f2bf(v0); w.y = f2bf(v1); w.z = f2bf(v2); w.w = f2bf(v3);
    Wb[n * 256 + i] = w;         // coalesced 8B/lane
}

// ---- kernel 2: fused cvt + 256x256-tile MFMA GEMM -------------------------
__device__ __forceinline__ void async_lds16(const void* g, void* l) {
    __builtin_amdgcn_global_load_lds(
        (const __attribute__((address_space(1))) unsigned int*)g,
        (__attribute__((address_space(3))) unsigned int*)l,
        16, 0, 0);
}

// Stage one B half-tile (128 rows x 64 bf16) into 16 subtiles of [16][32]
// bf16.  global_load_lds writes LINEAR (base + lane*16B); the st_16x32
// swizzle is achieved by inverse-swizzling the per-lane GLOBAL source.
__device__ __forceinline__ void stage_ht(const unsigned short* __restrict__ G,
                                         int row0, int k0,
                                         unsigned short* ht,
                                         int wave, int lane) {
    int sr = lane >> 2;                                     // subtile row 0..15
    int sc = ((lane & 3) * 8) ^ ((lane & 32) ? 16 : 0);     // swizzled col
#pragma unroll
    for (int j = 0; j < 2; ++j) {
        int si = j * 8 + wave;           // subtile 0..15
        int rg = si >> 1, cg = si & 1;   // row-group (16 rows), col-group (32)
        async_lds16(G + (size_t)(row0 + rg * 16 + sr) * K_TOT + k0 + cg * 32 + sc,
                    ht + si * 512);
    }
}

__global__ __launch_bounds__(512, 2) void gemm_fused(
        const float* __restrict__ X,            // [M][K] fp32 (activations)
        const unsigned short* __restrict__ B,   // [N][K] bf16 (combined W)
        const float* __restrict__ bias,         // [N]
        float* __restrict__ C) {                // [M][N] fp32
    __shared__ unsigned short smemA[2][2][8192];   // [buf][half][16 subtiles]
    __shared__ unsigned short smemB[2][2][8192];

    const int tid  = threadIdx.x;
    const int wave = tid >> 6;      // 0..7
    const int lane = tid & 63;
    const int quad = lane >> 4;     // 0..3
    const int r16  = lane & 15;     // 0..15
    const int wm   = wave & 1;      // wave grid 2(M) x 4(N); wave out: 128x64
    const int wn   = wave >> 1;     // 0..3

    // T1: bijective XCD swizzle (512 workgroups, 512 % 8 == 0)
    int bid = blockIdx.x;
    int wg  = (bid & 7) * 64 + (bid >> 3);
    const int m0 = (wg >> 2) * BM;
    const int n0 = (wg & 3) * BN;   // consecutive wg share the A panel

    // ---- precomputed lane-invariant LDS addressing (shorts) ----
    // fragment reads: row&15 == r16, row&8 == r16&8 for every fragment
    const int laneRd = (r16 * 32 + quad * 8) ^ ((r16 & 8) << 1);
    const unsigned short* baseA = &smemA[0][wm][0] + laneRd;
    const unsigned short* baseB = &smemB[0][wn >> 1][0] + (wn & 1) * 4096 + laneRd;

    // A staging: 512 lanes cover one quarter (rows {h*128 + q*64 + r64})
    const int qrow = tid >> 2;            // 0..127
    const int ah   = qrow >> 6;           // which 128-row half
    const int r64  = qrow & 63;           // row within quarter
    const int kb   = (tid & 3) * 16;      // fp32/bf16 column base
    const int wTerm = ah * 8192 +
        (((r64 >> 4) * 2 + (kb >> 5)) * 512 +
         ((((r64 & 15) * 32) + (kb & 31)) ^ ((r64 & 8) << 1)));
    unsigned short* baseW = &smemA[0][0][0] + wTerm;
    const float* gA = X + (size_t)(m0 + ah * 128 + r64) * K_TOT + kb;

    f32x4 acc[8][4];
#pragma unroll
    for (int i = 0; i < 8; ++i)
#pragma unroll
        for (int j = 0; j < 4; ++j)
            acc[i][j] = (f32x4){0.f, 0.f, 0.f, 0.f};

    float4 aq0, aq1, aq2, aq3;    // quarter-0 regs (issue P3, consume next P2)
    float4 bq0, bq1, bq2, bq3;    // quarter-1 regs (issue P2, consume P4)

    // ---- prologue: A tiles 0,1 via regs; B0 via gload; pre-issue A(t=2) q0.
    {
        float4 p0 = *(const float4*)(gA + 0);
        float4 p1 = *(const float4*)(gA + 4);
        float4 p2 = *(const float4*)(gA + 8);
        float4 p3 = *(const float4*)(gA + 12);
        float4 q0 = *(const float4*)(gA + 65536 + 0);    // +64 rows
        float4 q1 = *(const float4*)(gA + 65536 + 4);
        float4 q2 = *(const float4*)(gA + 65536 + 8);
        float4 q3 = *(const float4*)(gA + 65536 + 12);
        stage_ht(B, n0,       0, &smemB[0][0][0], wave, lane);
        stage_ht(B, n0 + 128, 0, &smemB[0][1][0], wave, lane);
        *(bf16x8*)(baseW + 0)        = cvt8(p0, p1);     // tile0 q0
        *(bf16x8*)(baseW + 8)        = cvt8(p2, p3);
        *(bf16x8*)(baseW + 4096)     = cvt8(q0, q1);     // tile0 q1
        *(bf16x8*)(baseW + 4096 + 8) = cvt8(q2, q3);
        p0 = *(const float4*)(gA + BK + 0);
        p1 = *(const float4*)(gA + BK + 4);
        p2 = *(const float4*)(gA + BK + 8);
        p3 = *(const float4*)(gA + BK + 12);
        q0 = *(const float4*)(gA + 65536 + BK + 0);
        q1 = *(const float4*)(gA + 65536 + BK + 4);
        q2 = *(const float4*)(gA + 65536 + BK + 8);
        q3 = *(const float4*)(gA + 65536 + BK + 12);
        *(bf16x8*)(baseW + 16384)        = cvt8(p0, p1); // tile1 q0
        *(bf16x8*)(baseW + 16384 + 8)    = cvt8(p2, p3);
        *(bf16x8*)(baseW + 20480)        = cvt8(q0, q1); // tile1 q1
        *(bf16x8*)(baseW + 20480 + 8)    = cvt8(q2, q3);
        // pre-issue tile2 q0 (consumed at t=0's P2)
        aq0 = *(const float4*)(gA + 2 * BK + 0);
        aq1 = *(const float4*)(gA + 2 * BK + 4);
        aq2 = *(const float4*)(gA + 2 * BK + 8);
        aq3 = *(const float4*)(gA + 2 * BK + 12);
        asm volatile("s_waitcnt vmcnt(4)" ::: "memory");   // drain B0; aq stays
        asm volatile("s_waitcnt lgkmcnt(0)" ::: "memory");
        __builtin_amdgcn_s_barrier();
    }

    bf16x8 af[4][2], bl[2][2], bh[2][2];

#pragma unroll 2
    for (int t = 0; t < NKT; ++t) {
        const int c  = t & 1;
        const int cA = c * 16384;   // buffer toggle, shorts

        // ---------- P1: read A-low + B-low frags; stage B(t+1) ----------
#pragma unroll
        for (int mb = 0; mb < 4; ++mb) {
            af[mb][0] = *(const bf16x8*)(baseA + cA + (mb * 2 + 0) * 512);
            af[mb][1] = *(const bf16x8*)(baseA + cA + (mb * 2 + 1) * 512);
        }
#pragma unroll
        for (int nb = 0; nb < 2; ++nb) {
            bl[nb][0] = *(const bf16x8*)(baseB + cA + (nb * 2 + 0) * 512);
            bl[nb][1] = *(const bf16x8*)(baseB + cA + (nb * 2 + 1) * 512);
        }
        if (t + 1 < NKT) {
            stage_ht(B, n0,       (t + 1) * BK, &smemB[c ^ 1][0][0], wave, lane);
            stage_ht(B, n0 + 128, (t + 1) * BK, &smemB[c ^ 1][1][0], wave, lane);
        }
        __builtin_amdgcn_s_barrier();
        asm volatile("s_waitcnt lgkmcnt(0)" ::: "memory");
        __builtin_amdgcn_s_setprio(1);
#pragma unroll
        for (int mb = 0; mb < 4; ++mb)
#pragma unroll
            for (int nb = 0; nb < 2; ++nb) {
                acc[mb][nb] = __builtin_amdgcn_mfma_f32_16x16x32_bf16(
                    af[mb][0], bl[nb][0], acc[mb][nb], 0, 0, 0);
                acc[mb][nb] = __builtin_amdgcn_mfma_f32_16x16x32_bf16(
                    af[mb][1], bl[nb][1], acc[mb][nb], 0, 0, 0);
            }
        __builtin_amdgcn_s_setprio(0);
        __builtin_amdgcn_s_barrier();

        // ---------- P2: read B-high; write A(t+2) q0; issue A(t+2) q1 -------
#pragma unroll
        for (int nb = 0; nb < 2; ++nb) {
            bh[nb][0] = *(const bf16x8*)(baseB + cA + ((nb + 2) * 2 + 0) * 512);
            bh[nb][1] = *(const bf16x8*)(baseB + cA + ((nb + 2) * 2 + 1) * 512);
        }
        if (t + 2 < NKT) {
            const int k2 = (t + 2) * BK;
            // rows 0..63 of each half were last read at P1 -> slots free
            *(bf16x8*)(baseW + cA + 0) = cvt8(aq0, aq1);   // auto vmcnt leaves B
            *(bf16x8*)(baseW + cA + 8) = cvt8(aq2, aq3);
            bq0 = *(const float4*)(gA + 65536 + k2 + 0);   // quarter-1
            bq1 = *(const float4*)(gA + 65536 + k2 + 4);
            bq2 = *(const float4*)(gA + 65536 + k2 + 8);
            bq3 = *(const float4*)(gA + 65536 + k2 + 12);
        }
        __builtin_amdgcn_s_barrier();
        asm volatile("s_waitcnt lgkmcnt(0)" ::: "memory");
        __builtin_amdgcn_s_setprio(1);
#pragma unroll
        for (int mb = 0; mb < 4; ++mb)
#pragma unroll
            for (int nb = 0; nb < 2; ++nb) {
                acc[mb][nb + 2] = __builtin_amdgcn_mfma_f32_16x16x32_bf16(
                    af[mb][0], bh[nb][0], acc[mb][nb + 2], 0, 0, 0);
                acc[mb][nb + 2] = __builtin_amdgcn_mfma_f32_16x16x32_bf16(
                    af[mb][1], bh[nb][1], acc[mb][nb + 2], 0, 0, 0);
            }
        __builtin_amdgcn_s_setprio(0);
        __builtin_amdgcn_s_barrier();

        // ---------- P3: read A-high frags; issue A(t+3) q0 ----------
#pragma unroll
        for (int mb = 0; mb < 4; ++mb) {
            af[mb][0] = *(const bf16x8*)(baseA + cA + ((mb + 4) * 2 + 0) * 512);
            af[mb][1] = *(const bf16x8*)(baseA + cA + ((mb + 4) * 2 + 1) * 512);
        }
        if (t + 3 < NKT) {
            const int k3 = (t + 3) * BK;
            aq0 = *(const float4*)(gA + k3 + 0);
            aq1 = *(const float4*)(gA + k3 + 4);
            aq2 = *(const float4*)(gA + k3 + 8);
            aq3 = *(const float4*)(gA + k3 + 12);
        }
        __builtin_amdgcn_s_barrier();
        asm volatile("s_waitcnt lgkmcnt(0)" ::: "memory");
        __builtin_amdgcn_s_setprio(1);
#pragma unroll
        for (int mb = 0; mb < 4; ++mb)
#pragma unroll
            for (int nb = 0; nb < 2; ++nb) {
                acc[mb + 4][nb + 2] = __builtin_amdgcn_mfma_f32_16x16x32_bf16(
                    af[mb][0], bh[nb][0], acc[mb + 4][nb + 2], 0, 0, 0);
                acc[mb + 4][nb + 2] = __builtin_amdgcn_mfma_f32_16x16x32_bf16(
                    af[mb][1], bh[nb][1], acc[mb + 4][nb + 2], 0, 0, 0);
            }
        __builtin_amdgcn_s_setprio(0);
        __builtin_amdgcn_s_barrier();

        // ---------- P4: MFMA (regs only); write A(t+2) q1; publish ----------
        __builtin_amdgcn_s_setprio(1);
#pragma unroll
        for (int mb = 0; mb < 4; ++mb)
#pragma unroll
            for (int nb = 0; nb < 2; ++nb) {
                acc[mb + 4][nb] = __builtin_amdgcn_mfma_f32_16x16x32_bf16(
                    af[mb][0], bl[nb][0], acc[mb + 4][nb], 0, 0, 0);
                acc[mb + 4][nb] = __builtin_amdgcn_mfma_f32_16x16x32_bf16(
                    af[mb][1], bl[nb][1], acc[mb + 4][nb], 0, 0, 0);
            }
        __builtin_amdgcn_s_setprio(0);
        if (t + 2 < NKT) {
            // rows 64..127 of each half were last read at P3 -> slots free
            *(bf16x8*)(baseW + cA + 4096)     = cvt8(bq0, bq1);
            *(bf16x8*)(baseW + cA + 4096 + 8) = cvt8(bq2, bq3);
            // bq's auto-wait retired B(t+1) too; aq (newest 4) stays in flight
            asm volatile("s_waitcnt vmcnt(4)" ::: "memory");
        } else if (t + 1 < NKT) {
            asm volatile("s_waitcnt vmcnt(0)" ::: "memory");   // tail drain
        }
        asm volatile("s_waitcnt lgkmcnt(0)" ::: "memory");
        __builtin_amdgcn_s_barrier();
    }

    // ---- epilogue: C/D layout col = lane&15 (N), row = quad*4 + reg (M) ----
    const int mbase = m0 + wm * 128 + quad * 4;
    const int nbase = n0 + wn * 64 + r16;
#pragma unroll
    for (int nb = 0; nb < 4; ++nb) {
        int col  = nbase + nb * 16;
        float bv = bias[col];
#pragma unroll
        for (int mb = 0; mb < 8; ++mb) {
            int rowb = mbase + mb * 16;
            f32x4 v  = acc[mb][nb];
#pragma unroll
            for (int r = 0; r < 4; ++r)
                C[(size_t)(rowb + r) * N_TOT + col] = v[r] + bv;
        }
    }
}

extern "C" void kernel_launch(void* const* d_in, const int* in_sizes, int n_in,
                              void* d_out, int out_size, void* d_ws, size_t ws_size,
                              hipStream_t stream) {
    const float* x    = (const float*)d_in[0];   // [4, 8192, 1024]
    const float* rw   = (const float*)d_in[1];   // [256, 256]
    const float* iw   = (const float*)d_in[2];
    const float* jw   = (const float*)d_in[3];
    const float* kw   = (const float*)d_in[4];
    const float* bias = (const float*)d_in[5];   // [1024]
    float* out = (float*)d_out;                  // [4, 8192, 1024]

    // workspace: combined W in bf16 (2 MiB) at base
    unsigned short* Wb = (unsigned short*)d_ws;

    // 1) build combined 1024x1024 bf16 weight (B^T layout), 1 block/row
    build_w<<<N_TOT, 256, 0, stream>>>(rw, iw, jw, kw, (ushort4*)Wb);

    // 2) fused cvt+GEMM: 128 x 4 tiles of 256x256, 512 threads (8 waves)
    gemm_fused<<<dim3((M_TOT / BM) * (N_TOT / BN)), 512, 0, stream>>>(
        x, Wb, bias, out);
}

// Round 4
// 296.512 us; speedup vs baseline: 1.1043x; 1.0634x over previous
//
#include <hip/hip_runtime.h>

// ---------------------------------------------------------------------------
// QuaternionLinear == one GEMM: out[M=32768][N=1024] = x[M][K=1024] * W^T + b.
// Round 4: round-3 structure (fused cvt+GEMM, mfma_f32_32x32x16_bf16,
// conflict-free A ds_writes, 256x256 tile, BK=64, 4 phases/K-tile, counted
// vmcnt, setprio, XCD swizzle) with the swizzle-carry bug FIXED: the
// ks-dependent col offset (+16) must live under the st_16x32 XOR, so the
// per-read col term is ((ks&1)<<4) ^ kx  (kx = (lane&8)<<1), not an add.
// ---------------------------------------------------------------------------

typedef __attribute__((ext_vector_type(8))) short bf16x8;    // 8 bf16 = 4 VGPRs
typedef __attribute__((ext_vector_type(16))) float f32x16;   // 32x32 acc tile

#define M_TOT 32768
#define N_TOT 1024
#define K_TOT 1024
#define BM 256
#define BN 256
#define BK 64
#define NKT (K_TOT / BK)   // 16 K-tiles

__device__ __forceinline__ unsigned short f2bf(float f) {
    union { float f; unsigned int u; } v; v.f = f;
    unsigned int u = v.u;
    u += 0x7fffu + ((u >> 16) & 1u);   // round-to-nearest-even
    return (unsigned short)(u >> 16);
}

__device__ __forceinline__ bf16x8 cvt8(float4 a, float4 b) {
    bf16x8 r;
    r[0] = (short)f2bf(a.x); r[1] = (short)f2bf(a.y);
    r[2] = (short)f2bf(a.z); r[3] = (short)f2bf(a.w);
    r[4] = (short)f2bf(b.x); r[5] = (short)f2bf(b.y);
    r[6] = (short)f2bf(b.z); r[7] = (short)f2bf(b.w);
    return r;
}

// ---- kernel 1: combined quaternion weight matrix, bf16, [N][K] (B^T) ------
__global__ __launch_bounds__(256) void build_w(const float* __restrict__ R,
                                               const float* __restrict__ I,
                                               const float* __restrict__ J,
                                               const float* __restrict__ Kw,
                                               ushort4* __restrict__ Wb) {
    int n = blockIdx.x;          // 0..1023 (output row of W)
    int i = threadIdx.x;         // 0..255  (input quaternion index)
    int o = n >> 2, co = n & 3;
    int base = o * 256 + i;
    float r = R[base], ii = I[base], j = J[base], k = Kw[base];
    float v0, v1, v2, v3;
    if (co == 0)      { v0 = r;  v1 = -ii; v2 = -j;  v3 = -k; }
    else if (co == 1) { v0 = ii; v1 = r;   v2 = k;   v3 = -j; }
    else if (co == 2) { v0 = j;  v1 = -k;  v2 = r;   v3 = ii; }
    else              { v0 = k;  v1 = j;   v2 = -ii; v3 = r;  }
    ushort4 w;
    w.x = f2bf(v0); w.y = f2bf(v1); w.z = f2bf(v2); w.w = f2bf(v3);
    Wb[n * 256 + i] = w;         // coalesced 8B/lane
}

// ---- kernel 2: fused cvt + 256x256-tile MFMA GEMM -------------------------
__device__ __forceinline__ void async_lds16(const void* g, void* l) {
    __builtin_amdgcn_global_load_lds(
        (const __attribute__((address_space(1))) unsigned int*)g,
        (__attribute__((address_space(3))) unsigned int*)l,
        16, 0, 0);
}

// Stage one B half-tile (128 rows x 64 bf16) into 16 subtiles of [16][32]
// bf16 (st_16x32 swizzle via inverse-swizzled global source; LDS linear).
__device__ __forceinline__ void stage_ht(const unsigned short* __restrict__ G,
                                         int row0, int k0,
                                         unsigned short* ht,
                                         int wave, int lane) {
    int sr = lane >> 2;                                     // subtile row 0..15
    int sc = ((lane & 3) * 8) ^ ((lane & 32) ? 16 : 0);     // swizzled col
#pragma unroll
    for (int j = 0; j < 2; ++j) {
        int si = j * 8 + wave;           // subtile 0..15
        int rg = si >> 1, cg = si & 1;   // row-group (16 rows), col-group (32)
        async_lds16(G + (size_t)(row0 + rg * 16 + sr) * K_TOT + k0 + cg * 32 + sc,
                    ht + si * 512);
    }
}

__global__ __launch_bounds__(512, 2) void gemm_fused(
        const float* __restrict__ X,            // [M][K] fp32 (activations)
        const unsigned short* __restrict__ B,   // [N][K] bf16 (combined W)
        const float* __restrict__ bias,         // [N]
        float* __restrict__ C) {                // [M][N] fp32
    __shared__ unsigned short smemA[2][2][8192];   // [buf][half][16 subtiles]
    __shared__ unsigned short smemB[2][2][8192];

    const int tid  = threadIdx.x;
    const int wave = tid >> 6;      // 0..7
    const int lane = tid & 63;
    const int wm   = wave & 1;      // wave grid 2(M) x 4(N); wave out: 128x64
    const int wn   = wave >> 1;     // 0..3

    // T1: bijective XCD swizzle (512 workgroups, 512 % 8 == 0)
    int bid = blockIdx.x;
    int wg  = (bid & 7) * 64 + (bid >> 3);
    const int m0 = (wg >> 2) * BM;
    const int n0 = (wg & 3) * BN;   // consecutive wg share the A panel

    // ---- fragment-read lane base (shorts), 32x32x16 operand layout:
    // row/col = lane&31, k = (lane>>5)*8 + j (8 contiguous bf16).
    // Storage rule: within-subtile col is XORed with 16 when row&8.  The
    // ks-dependent col bit (+16 for odd ks) must be under the XOR:
    //   col_stored = (((ks&1)<<4) ^ kx) + klo8,  kx = (lane&8)<<1.
    const int laneRd = (lane & 15) * 32          // row within subtile
                     + ((lane >> 4) & 1) * 1024  // rows 16-31 -> next row-group
                     + ((lane >> 5) & 1) * 8;    // k-low: 8-elem group
    const int kx  = (lane & 8) << 1;             // swizzle XOR (shorts)
    const int kofs[2] = { kx, kx ^ 16 };         // col term for ks even/odd
    const unsigned short* baseA = &smemA[0][wm][0] + laneRd;
    const unsigned short* baseB = &smemB[0][wn >> 1][0] + (wn & 1) * 4096 + laneRd;

    // ---- A staging role: wave = subtile-within-quarter, lane = (row, kchunk)
    // wave w covers subtile (rg = w>>1, cg = w&1); lane: row = lane>>2,
    // kchunk = lane&3 (4 consecutive 16B slots per row -> conflict-free).
    const int srow = (lane >> 2) & 15;
    const int skc  = lane & 3;
    unsigned short* wbase = &smemA[0][0][0] + wave * 512
                          + (((srow * 32) + skc * 8) ^ ((lane & 32) ? 16 : 0));
    const float* gBase = X + (size_t)(m0 + (wave >> 1) * 16 + srow) * K_TOT
                       + (wave & 1) * 32 + skc * 8;
    // offsets: +h*131072 floats (half), +rh*65536 floats (row-half), +k0

    f32x16 acc[4][2];
#pragma unroll
    for (int i = 0; i < 4; ++i)
#pragma unroll
        for (int j = 0; j < 2; ++j)
#pragma unroll
            for (int r = 0; r < 16; ++r)
                acc[i][j][r] = 0.f;

    float4 aq0a, aq0b, aq1a, aq1b;   // A(t+2) rh0 (h0,h1): issue P3, write P2
    float4 bq0a, bq0b, bq1a, bq1b;   // A(t+2) rh1 (h0,h1): issue P2, write P4

    // ---- prologue: B(0) via DMA; A tiles 0,1 via reg path; pre-issue A(2) rh0
    stage_ht(B, n0,       0, &smemB[0][0][0], wave, lane);
    stage_ht(B, n0 + 128, 0, &smemB[0][1][0], wave, lane);
#pragma unroll
    for (int tt = 0; tt < 2; ++tt)
#pragma unroll
        for (int rh = 0; rh < 2; ++rh)
#pragma unroll
            for (int h = 0; h < 2; ++h) {
                const float* g = gBase + (size_t)h * 131072 + rh * 65536 + tt * BK;
                float4 a = *(const float4*)g;
                float4 b = *(const float4*)(g + 4);
                *(bf16x8*)(wbase + tt * 16384 + h * 8192 + rh * 4096) = cvt8(a, b);
            }
    aq0a = *(const float4*)(gBase + 2 * BK);
    aq0b = *(const float4*)(gBase + 2 * BK + 4);
    aq1a = *(const float4*)(gBase + 131072 + 2 * BK);
    aq1b = *(const float4*)(gBase + 131072 + 2 * BK + 4);
    asm volatile("s_waitcnt vmcnt(4)" ::: "memory");   // B(0) done; aq in flight
    asm volatile("s_waitcnt lgkmcnt(0)" ::: "memory");
    __builtin_amdgcn_s_barrier();

    bf16x8 af[2][4], bl[4], bh[4];

#pragma unroll 2
    for (int t = 0; t < NKT; ++t) {
        const int c  = t & 1;
        const int cA = c * 16384;   // buffer toggle, shorts

        // ---------- P1: read A rb0-1 + B cb0; stage B(t+1) ----------
#pragma unroll
        for (int rb = 0; rb < 2; ++rb)
#pragma unroll
            for (int ks = 0; ks < 4; ++ks)
                af[rb][ks] = *(const bf16x8*)(baseA + cA + rb * 2048
                                              + (ks >> 1) * 512 + kofs[ks & 1]);
#pragma unroll
        for (int ks = 0; ks < 4; ++ks)
            bl[ks] = *(const bf16x8*)(baseB + cA + (ks >> 1) * 512 + kofs[ks & 1]);
        if (t + 1 < NKT) {
            stage_ht(B, n0,       (t + 1) * BK, &smemB[c ^ 1][0][0], wave, lane);
            stage_ht(B, n0 + 128, (t + 1) * BK, &smemB[c ^ 1][1][0], wave, lane);
        }
        __builtin_amdgcn_s_barrier();
        asm volatile("s_waitcnt lgkmcnt(0)" ::: "memory");
        __builtin_amdgcn_s_setprio(1);
#pragma unroll
        for (int rb = 0; rb < 2; ++rb)
#pragma unroll
            for (int ks = 0; ks < 4; ++ks)
                acc[rb][0] = __builtin_amdgcn_mfma_f32_32x32x16_bf16(
                    af[rb][ks], bl[ks], acc[rb][0], 0, 0, 0);
        __builtin_amdgcn_s_setprio(0);
        __builtin_amdgcn_s_barrier();

        // ---------- P2: read B cb1; write A(t+2) rh0; issue A(t+2) rh1 ------
#pragma unroll
        for (int ks = 0; ks < 4; ++ks)
            bh[ks] = *(const bf16x8*)(baseB + cA + 2048
                                      + (ks >> 1) * 512 + kofs[ks & 1]);
        if (t + 2 < NKT) {
            const int k2 = (t + 2) * BK;
            *(bf16x8*)(wbase + cA)        = cvt8(aq0a, aq0b);   // h0 rh0
            *(bf16x8*)(wbase + cA + 8192) = cvt8(aq1a, aq1b);   // h1 rh0
            bq0a = *(const float4*)(gBase + 65536 + k2);
            bq0b = *(const float4*)(gBase + 65536 + k2 + 4);
            bq1a = *(const float4*)(gBase + 131072 + 65536 + k2);
            bq1b = *(const float4*)(gBase + 131072 + 65536 + k2 + 4);
        }
        __builtin_amdgcn_s_barrier();
        asm volatile("s_waitcnt lgkmcnt(0)" ::: "memory");
        __builtin_amdgcn_s_setprio(1);
#pragma unroll
        for (int rb = 0; rb < 2; ++rb)
#pragma unroll
            for (int ks = 0; ks < 4; ++ks)
                acc[rb][1] = __builtin_amdgcn_mfma_f32_32x32x16_bf16(
                    af[rb][ks], bh[ks], acc[rb][1], 0, 0, 0);
        __builtin_amdgcn_s_setprio(0);
        __builtin_amdgcn_s_barrier();

        // ---------- P3: read A rb2-3; issue A(t+3) rh0 ----------
#pragma unroll
        for (int rb = 0; rb < 2; ++rb)
#pragma unroll
            for (int ks = 0; ks < 4; ++ks)
                af[rb][ks] = *(const bf16x8*)(baseA + cA + (rb + 2) * 2048
                                              + (ks >> 1) * 512 + kofs[ks & 1]);
        if (t + 3 < NKT) {
            const int k3 = (t + 3) * BK;
            aq0a = *(const float4*)(gBase + k3);
            aq0b = *(const float4*)(gBase + k3 + 4);
            aq1a = *(const float4*)(gBase + 131072 + k3);
            aq1b = *(const float4*)(gBase + 131072 + k3 + 4);
        }
        __builtin_amdgcn_s_barrier();
        asm volatile("s_waitcnt lgkmcnt(0)" ::: "memory");
        __builtin_amdgcn_s_setprio(1);
#pragma unroll
        for (int rb = 0; rb < 2; ++rb)
#pragma unroll
            for (int ks = 0; ks < 4; ++ks)
                acc[rb + 2][1] = __builtin_amdgcn_mfma_f32_32x32x16_bf16(
                    af[rb][ks], bh[ks], acc[rb + 2][1], 0, 0, 0);
        __builtin_amdgcn_s_setprio(0);
        __builtin_amdgcn_s_barrier();

        // ---------- P4: MFMA (regs only); write A(t+2) rh1; publish ---------
        __builtin_amdgcn_s_setprio(1);
#pragma unroll
        for (int rb = 0; rb < 2; ++rb)
#pragma unroll
            for (int ks = 0; ks < 4; ++ks)
                acc[rb + 2][0] = __builtin_amdgcn_mfma_f32_32x32x16_bf16(
                    af[rb][ks], bl[ks], acc[rb + 2][0], 0, 0, 0);
        __builtin_amdgcn_s_setprio(0);
        if (t + 2 < NKT) {
            *(bf16x8*)(wbase + cA + 4096)        = cvt8(bq0a, bq0b);  // h0 rh1
            *(bf16x8*)(wbase + cA + 8192 + 4096) = cvt8(bq1a, bq1b);  // h1 rh1
            // bq's implicit wait retired B(t+1) too; aq (newest 4) stays live
            asm volatile("s_waitcnt vmcnt(4)" ::: "memory");
        } else if (t + 1 < NKT) {
            asm volatile("s_waitcnt vmcnt(0)" ::: "memory");   // tail drain
        }
        asm volatile("s_waitcnt lgkmcnt(0)" ::: "memory");
        __builtin_amdgcn_s_barrier();
    }

    // ---- epilogue: 32x32 C/D layout: col = lane&31,
    // row = (reg&3) + 8*(reg>>2) + 4*(lane>>5)
    const int mbase = m0 + wm * 128 + ((lane >> 5) & 1) * 4;
    const int nbase = n0 + wn * 64 + (lane & 31);
#pragma unroll
    for (int cb = 0; cb < 2; ++cb) {
        int col  = nbase + cb * 32;
        float bv = bias[col];
#pragma unroll
        for (int rb = 0; rb < 4; ++rb) {
            f32x16 v = acc[rb][cb];
#pragma unroll
            for (int r = 0; r < 16; ++r) {
                int row = mbase + rb * 32 + (r & 3) + (r >> 2) * 8;
                C[(size_t)row * N_TOT + col] = v[r] + bv;
            }
        }
    }
}

extern "C" void kernel_launch(void* const* d_in, const int* in_sizes, int n_in,
                              void* d_out, int out_size, void* d_ws, size_t ws_size,
                              hipStream_t stream) {
    const float* x    = (const float*)d_in[0];   // [4, 8192, 1024]
    const float* rw   = (const float*)d_in[1];   // [256, 256]
    const float* iw   = (const float*)d_in[2];
    const float* jw   = (const float*)d_in[3];
    const float* kw   = (const float*)d_in[4];
    const float* bias = (const float*)d_in[5];   // [1024]
    float* out = (float*)d_out;                  // [4, 8192, 1024]

    // workspace: combined W in bf16 (2 MiB) at base
    unsigned short* Wb = (unsigned short*)d_ws;

    // 1) build combined 1024x1024 bf16 weight (B^T layout), 1 block/row
    build_w<<<N_TOT, 256, 0, stream>>>(rw, iw, jw, kw, (ushort4*)Wb);

    // 2) fused cvt+GEMM: 128 x 4 tiles of 256x256, 512 threads (8 waves)
    gemm_fused<<<dim3((M_TOT / BM) * (N_TOT / BN)), 512, 0, stream>>>(
        x, Wb, bias, out);
}

// Round 5
// 296.051 us; speedup vs baseline: 1.1061x; 1.0016x over previous
//
#include <hip/hip_runtime.h>

// ---------------------------------------------------------------------------
// QuaternionLinear == one GEMM: out[M=32768][N=1024] = x[M][K=1024] * W^T + b.
// Round 5: round-4 structure (fused cvt+GEMM, mfma_f32_32x32x16_bf16,
// 256x256 tile, BK=64, 4 phases/K-tile, counted vmcnt, setprio, XCD swizzle)
// with two fixes:
//  (a) hardware v_cvt_pk_bf16_f32 for fp32->bf16 (was ~4 VALU/elem manual RNE)
//  (b) row-group-parity XOR-24 added to the LDS col swizzle at all 3 sites
//      (A ds_write, B DMA source, fragment reads) so quarter-waves no longer
//      have per-lane identical bank addresses (round-4's +4.2M conflicts).
// ---------------------------------------------------------------------------

typedef __attribute__((ext_vector_type(8))) short bf16x8;    // 8 bf16 = 4 VGPRs
typedef __attribute__((ext_vector_type(16))) float f32x16;   // 32x32 acc tile

#define M_TOT 32768
#define N_TOT 1024
#define K_TOT 1024
#define BM 256
#define BN 256
#define BK 64
#define NKT (K_TOT / BK)   // 16 K-tiles

__device__ __forceinline__ unsigned short f2bf(float f) {
    union { float f; unsigned int u; } v; v.f = f;
    unsigned int u = v.u;
    u += 0x7fffu + ((u >> 16) & 1u);   // round-to-nearest-even
    return (unsigned short)(u >> 16);
}

// HW packed fp32->bf16 (RNE), T12 recipe: no builtin on gfx950, inline asm.
// Non-volatile: pure value flow, compiler remains free to schedule.
__device__ __forceinline__ unsigned int pk2(float lo, float hi) {
    unsigned int r;
    asm("v_cvt_pk_bf16_f32 %0, %1, %2" : "=v"(r) : "v"(lo), "v"(hi));
    return r;
}

__device__ __forceinline__ bf16x8 cvt8(float4 a, float4 b) {
    union { unsigned int u[4]; bf16x8 v; } r;
    r.u[0] = pk2(a.x, a.y); r.u[1] = pk2(a.z, a.w);
    r.u[2] = pk2(b.x, b.y); r.u[3] = pk2(b.z, b.w);
    return r.v;
}

// ---- kernel 1: combined quaternion weight matrix, bf16, [N][K] (B^T) ------
__global__ __launch_bounds__(256) void build_w(const float* __restrict__ R,
                                               const float* __restrict__ I,
                                               const float* __restrict__ J,
                                               const float* __restrict__ Kw,
                                               ushort4* __restrict__ Wb) {
    int n = blockIdx.x;          // 0..1023 (output row of W)
    int i = threadIdx.x;         // 0..255  (input quaternion index)
    int o = n >> 2, co = n & 3;
    int base = o * 256 + i;
    float r = R[base], ii = I[base], j = J[base], k = Kw[base];
    float v0, v1, v2, v3;
    if (co == 0)      { v0 = r;  v1 = -ii; v2 = -j;  v3 = -k; }
    else if (co == 1) { v0 = ii; v1 = r;   v2 = k;   v3 = -j; }
    else if (co == 2) { v0 = j;  v1 = -k;  v2 = r;   v3 = ii; }
    else              { v0 = k;  v1 = j;   v2 = -ii; v3 = r;  }
    ushort4 w;
    w.x = f2bf(v0); w.y = f2bf(v1); w.z = f2bf(v2); w.w = f2bf(v3);
    Wb[n * 256 + i] = w;         // coalesced 8B/lane
}

// ---- kernel 2: fused cvt + 256x256-tile MFMA GEMM -------------------------
__device__ __forceinline__ void async_lds16(const void* g, void* l) {
    __builtin_amdgcn_global_load_lds(
        (const __attribute__((address_space(1))) unsigned int*)g,
        (__attribute__((address_space(3))) unsigned int*)l,
        16, 0, 0);
}

// Stage one B half-tile (128 rows x 64 bf16) into 16 subtiles of [16][32]
// bf16.  Storage swizzle (shorts, within-row bits 3-4):
//   cs = c ^ (16 if row&8) ^ (24 if rowgroup&1)
// global_load_lds writes LINEAR, so the swizzle is applied by inverse-
// permuting the per-lane GLOBAL source column.
__device__ __forceinline__ void stage_ht(const unsigned short* __restrict__ G,
                                         int row0, int k0,
                                         unsigned short* ht,
                                         int wave, int lane) {
    int sr = lane >> 2;                                     // subtile row 0..15
    int sc = ((lane & 3) * 8) ^ ((lane & 32) ? 16 : 0)      // row&8 swizzle
           ^ (((wave >> 1) & 1) ? 24 : 0);                  // rowgroup swizzle
#pragma unroll
    for (int j = 0; j < 2; ++j) {
        int si = j * 8 + wave;           // subtile 0..15 (rg parity = (w>>1)&1)
        int rg = si >> 1, cg = si & 1;   // row-group (16 rows), col-group (32)
        async_lds16(G + (size_t)(row0 + rg * 16 + sr) * K_TOT + k0 + cg * 32 + sc,
                    ht + si * 512);
    }
}

__global__ __launch_bounds__(512, 2) void gemm_fused(
        const float* __restrict__ X,            // [M][K] fp32 (activations)
        const unsigned short* __restrict__ B,   // [N][K] bf16 (combined W)
        const float* __restrict__ bias,         // [N]
        float* __restrict__ C) {                // [M][N] fp32
    __shared__ unsigned short smemA[2][2][8192];   // [buf][half][16 subtiles]
    __shared__ unsigned short smemB[2][2][8192];

    const int tid  = threadIdx.x;
    const int wave = tid >> 6;      // 0..7
    const int lane = tid & 63;
    const int wm   = wave & 1;      // wave grid 2(M) x 4(N); wave out: 128x64
    const int wn   = wave >> 1;     // 0..3

    // T1: bijective XCD swizzle (512 workgroups, 512 % 8 == 0)
    int bid = blockIdx.x;
    int wg  = (bid & 7) * 64 + (bid >> 3);
    const int m0 = (wg >> 2) * BM;
    const int n0 = (wg & 3) * BN;   // consecutive wg share the A panel

    // ---- fragment-read lane base (shorts), 32x32x16 operand layout:
    // row/col = lane&31, k = (lane>>5)*8 + j (8 contiguous bf16).
    // Storage col = logical ^ (16 if row&8) ^ (24 if rowgroup&1); the
    // k-low-8 bit (bit3) and ks&1 bit (bit4) must be XOR-composed too.
    const int laneRd = (lane & 15) * 32          // row within subtile
                     + ((lane >> 4) & 1) * 1024; // rows 16-31 -> rowgroup+1
    const int klo8 = ((lane >> 5) & 1) << 3;     // k-low 8-elem group (bit3)
    const int rxor = ((lane & 8) << 1)           // row&8 -> XOR 16
                   ^ (((lane >> 4) & 1) ? 24 : 0);  // rowgroup -> XOR 24
    const int kofs[2] = { klo8 ^ rxor, (klo8 ^ rxor) ^ 16 };  // ks even/odd
    const unsigned short* baseA = &smemA[0][wm][0] + laneRd;
    const unsigned short* baseB = &smemB[0][wn >> 1][0] + (wn & 1) * 4096 + laneRd;

    // ---- A staging role: wave = subtile (rg=w>>1, cg=w&1), lane = (row, kc)
    const int srow = (lane >> 2) & 15;
    const int skc  = lane & 3;
    unsigned short* wbase = &smemA[0][0][0] + wave * 512 + srow * 32
                          + ((skc * 8) ^ ((lane & 32) ? 16 : 0)
                                       ^ (((wave >> 1) & 1) ? 24 : 0));
    const float* gBase = X + (size_t)(m0 + (wave >> 1) * 16 + srow) * K_TOT
                       + (wave & 1) * 32 + skc * 8;
    // offsets: +h*131072 floats (half), +rh*65536 floats (row-half), +k0

    f32x16 acc[4][2];
#pragma unroll
    for (int i = 0; i < 4; ++i)
#pragma unroll
        for (int j = 0; j < 2; ++j)
#pragma unroll
            for (int r = 0; r < 16; ++r)
                acc[i][j][r] = 0.f;

    float4 aq0a, aq0b, aq1a, aq1b;   // A(t+2) rh0 (h0,h1): issue P3, write P2
    float4 bq0a, bq0b, bq1a, bq1b;   // A(t+2) rh1 (h0,h1): issue P2, write P4

    // ---- prologue: B(0) via DMA; A tiles 0,1 via reg path; pre-issue A(2) rh0
    stage_ht(B, n0,       0, &smemB[0][0][0], wave, lane);
    stage_ht(B, n0 + 128, 0, &smemB[0][1][0], wave, lane);
#pragma unroll
    for (int tt = 0; tt < 2; ++tt)
#pragma unroll
        for (int rh = 0; rh < 2; ++rh)
#pragma unroll
            for (int h = 0; h < 2; ++h) {
                const float* g = gBase + (size_t)h * 131072 + rh * 65536 + tt * BK;
                float4 a = *(const float4*)g;
                float4 b = *(const float4*)(g + 4);
                *(bf16x8*)(wbase + tt * 16384 + h * 8192 + rh * 4096) = cvt8(a, b);
            }
    aq0a = *(const float4*)(gBase + 2 * BK);
    aq0b = *(const float4*)(gBase + 2 * BK + 4);
    aq1a = *(const float4*)(gBase + 131072 + 2 * BK);
    aq1b = *(const float4*)(gBase + 131072 + 2 * BK + 4);
    asm volatile("s_waitcnt vmcnt(4)" ::: "memory");   // B(0) done; aq in flight
    asm volatile("s_waitcnt lgkmcnt(0)" ::: "memory");
    __builtin_amdgcn_s_barrier();

    bf16x8 af[2][4], bl[4], bh[4];

#pragma unroll 2
    for (int t = 0; t < NKT; ++t) {
        const int c  = t & 1;
        const int cA = c * 16384;   // buffer toggle, shorts

        // ---------- P1: read A rb0-1 + B cb0; stage B(t+1) ----------
#pragma unroll
        for (int rb = 0; rb < 2; ++rb)
#pragma unroll
            for (int ks = 0; ks < 4; ++ks)
                af[rb][ks] = *(const bf16x8*)(baseA + cA + rb * 2048
                                              + (ks >> 1) * 512 + kofs[ks & 1]);
#pragma unroll
        for (int ks = 0; ks < 4; ++ks)
            bl[ks] = *(const bf16x8*)(baseB + cA + (ks >> 1) * 512 + kofs[ks & 1]);
        if (t + 1 < NKT) {
            stage_ht(B, n0,       (t + 1) * BK, &smemB[c ^ 1][0][0], wave, lane);
            stage_ht(B, n0 + 128, (t + 1) * BK, &smemB[c ^ 1][1][0], wave, lane);
        }
        __builtin_amdgcn_s_barrier();
        asm volatile("s_waitcnt lgkmcnt(0)" ::: "memory");
        __builtin_amdgcn_s_setprio(1);
#pragma unroll
        for (int rb = 0; rb < 2; ++rb)
#pragma unroll
            for (int ks = 0; ks < 4; ++ks)
                acc[rb][0] = __builtin_amdgcn_mfma_f32_32x32x16_bf16(
                    af[rb][ks], bl[ks], acc[rb][0], 0, 0, 0);
        __builtin_amdgcn_s_setprio(0);
        __builtin_amdgcn_s_barrier();

        // ---------- P2: read B cb1; write A(t+2) rh0; issue A(t+2) rh1 ------
#pragma unroll
        for (int ks = 0; ks < 4; ++ks)
            bh[ks] = *(const bf16x8*)(baseB + cA + 2048
                                      + (ks >> 1) * 512 + kofs[ks & 1]);
        if (t + 2 < NKT) {
            const int k2 = (t + 2) * BK;
            *(bf16x8*)(wbase + cA)        = cvt8(aq0a, aq0b);   // h0 rh0
            *(bf16x8*)(wbase + cA + 8192) = cvt8(aq1a, aq1b);   // h1 rh0
            bq0a = *(const float4*)(gBase + 65536 + k2);
            bq0b = *(const float4*)(gBase + 65536 + k2 + 4);
            bq1a = *(const float4*)(gBase + 131072 + 65536 + k2);
            bq1b = *(const float4*)(gBase + 131072 + 65536 + k2 + 4);
        }
        __builtin_amdgcn_s_barrier();
        asm volatile("s_waitcnt lgkmcnt(0)" ::: "memory");
        __builtin_amdgcn_s_setprio(1);
#pragma unroll
        for (int rb = 0; rb < 2; ++rb)
#pragma unroll
            for (int ks = 0; ks < 4; ++ks)
                acc[rb][1] = __builtin_amdgcn_mfma_f32_32x32x16_bf16(
                    af[rb][ks], bh[ks], acc[rb][1], 0, 0, 0);
        __builtin_amdgcn_s_setprio(0);
        __builtin_amdgcn_s_barrier();

        // ---------- P3: read A rb2-3; issue A(t+3) rh0 ----------
#pragma unroll
        for (int rb = 0; rb < 2; ++rb)
#pragma unroll
            for (int ks = 0; ks < 4; ++ks)
                af[rb][ks] = *(const bf16x8*)(baseA + cA + (rb + 2) * 2048
                                              + (ks >> 1) * 512 + kofs[ks & 1]);
        if (t + 3 < NKT) {
            const int k3 = (t + 3) * BK;
            aq0a = *(const float4*)(gBase + k3);
            aq0b = *(const float4*)(gBase + k3 + 4);
            aq1a = *(const float4*)(gBase + 131072 + k3);
            aq1b = *(const float4*)(gBase + 131072 + k3 + 4);
        }
        __builtin_amdgcn_s_barrier();
        asm volatile("s_waitcnt lgkmcnt(0)" ::: "memory");
        __builtin_amdgcn_s_setprio(1);
#pragma unroll
        for (int rb = 0; rb < 2; ++rb)
#pragma unroll
            for (int ks = 0; ks < 4; ++ks)
                acc[rb + 2][1] = __builtin_amdgcn_mfma_f32_32x32x16_bf16(
                    af[rb][ks], bh[ks], acc[rb + 2][1], 0, 0, 0);
        __builtin_amdgcn_s_setprio(0);
        __builtin_amdgcn_s_barrier();

        // ---------- P4: MFMA (regs only); write A(t+2) rh1; publish ---------
        __builtin_amdgcn_s_setprio(1);
#pragma unroll
        for (int rb = 0; rb < 2; ++rb)
#pragma unroll
            for (int ks = 0; ks < 4; ++ks)
                acc[rb + 2][0] = __builtin_amdgcn_mfma_f32_32x32x16_bf16(
                    af[rb][ks], bl[ks], acc[rb + 2][0], 0, 0, 0);
        __builtin_amdgcn_s_setprio(0);
        if (t + 2 < NKT) {
            *(bf16x8*)(wbase + cA + 4096)        = cvt8(bq0a, bq0b);  // h0 rh1
            *(bf16x8*)(wbase + cA + 8192 + 4096) = cvt8(bq1a, bq1b);  // h1 rh1
            // bq's implicit wait retired B(t+1) too; aq (newest 4) stays live
            asm volatile("s_waitcnt vmcnt(4)" ::: "memory");
        } else if (t + 1 < NKT) {
            asm volatile("s_waitcnt vmcnt(0)" ::: "memory");   // tail drain
        }
        asm volatile("s_waitcnt lgkmcnt(0)" ::: "memory");
        __builtin_amdgcn_s_barrier();
    }

    // ---- epilogue: 32x32 C/D layout: col = lane&31,
    // row = (reg&3) + 8*(reg>>2) + 4*(lane>>5)
    const int mbase = m0 + wm * 128 + ((lane >> 5) & 1) * 4;
    const int nbase = n0 + wn * 64 + (lane & 31);
#pragma unroll
    for (int cb = 0; cb < 2; ++cb) {
        int col  = nbase + cb * 32;
        float bv = bias[col];
#pragma unroll
        for (int rb = 0; rb < 4; ++rb) {
            f32x16 v = acc[rb][cb];
#pragma unroll
            for (int r = 0; r < 16; ++r) {
                int row = mbase + rb * 32 + (r & 3) + (r >> 2) * 8;
                C[(size_t)row * N_TOT + col] = v[r] + bv;
            }
        }
    }
}

extern "C" void kernel_launch(void* const* d_in, const int* in_sizes, int n_in,
                              void* d_out, int out_size, void* d_ws, size_t ws_size,
                              hipStream_t stream) {
    const float* x    = (const float*)d_in[0];   // [4, 8192, 1024]
    const float* rw   = (const float*)d_in[1];   // [256, 256]
    const float* iw   = (const float*)d_in[2];
    const float* jw   = (const float*)d_in[3];
    const float* kw   = (const float*)d_in[4];
    const float* bias = (const float*)d_in[5];   // [1024]
    float* out = (float*)d_out;                  // [4, 8192, 1024]

    // workspace: combined W in bf16 (2 MiB) at base
    unsigned short* Wb = (unsigned short*)d_ws;

    // 1) build combined 1024x1024 bf16 weight (B^T layout), 1 block/row
    build_w<<<N_TOT, 256, 0, stream>>>(rw, iw, jw, kw, (ushort4*)Wb);

    // 2) fused cvt+GEMM: 128 x 4 tiles of 256x256, 512 threads (8 waves)
    gemm_fused<<<dim3((M_TOT / BM) * (N_TOT / BN)), 512, 0, stream>>>(
        x, Wb, bias, out);
}